// Round 8
// baseline (202.126 us; speedup 1.0000x reference)
//
#include <hip/hip_runtime.h>
#include <hip/hip_bf16.h>
#include <math.h>
#include <stdint.h>

#define B_ 2
#define T_ 2048
#define C_ 1024
#define H_ 16
#define D_ 64

typedef __attribute__((ext_vector_type(8))) short bf16x8;
typedef __attribute__((ext_vector_type(4))) float f32x4;

__device__ inline short f2bf(float f) {
  __hip_bfloat16 h = __float2bfloat16(f);
  return *(short*)&h;
}

// async global->LDS, 16B/lane. LDS image = wave-uniform base + lane*16.
__device__ inline void async16(const void* g, void* l) {
  __builtin_amdgcn_global_load_lds(
      (const __attribute__((address_space(1))) uint32_t*)g,
      (__attribute__((address_space(3))) uint32_t*)l, 16, 0, 0);
}

// ---------------------------------------------------------------------------
// Swizzle convention for GEMM operand images (A [M,1024] and B^T [N,1024]):
// chunk p of each 32-k group holds source chunk (p ^ ((row>>1)&3)).
// Fragment reads use chunk (quad ^ ((l16>>1)&3)) -> 2-way banks (free).
// ---------------------------------------------------------------------------

// One prep kernel: blocks [0,512) convert x -> bf16 swizzled;
// [512,1280) transpose w_qkv; [1280,1536) transpose w_proj.
__global__ __launch_bounds__(256) void prep(
    const float* __restrict__ X, const float* __restrict__ Wq,
    const float* __restrict__ Wp, short* __restrict__ Xb,
    short* __restrict__ Wqt, short* __restrict__ Wpt) {
  const int tid = threadIdx.x;
  const int blk = blockIdx.x;
  __shared__ short Ts[64][68];

  if (blk < 512) {  // convert_x: one 32-k group per thread
    int t = blk * 256 + tid;
    int m = t >> 5, g = t & 31;
    const float* src = X + (size_t)m * C_ + g * 32;
    short* dst = Xb + (size_t)m * C_ + g * 32;
    int xv = (m >> 1) & 3;
    short out[32];
#pragma unroll
    for (int ch = 0; ch < 4; ++ch) {
      int sc = ch ^ xv;
#pragma unroll
      for (int e = 0; e < 8; e += 4) {
        float4 v = *(const float4*)(src + sc * 8 + e);
        out[ch * 8 + e + 0] = f2bf(v.x);
        out[ch * 8 + e + 1] = f2bf(v.y);
        out[ch * 8 + e + 2] = f2bf(v.z);
        out[ch * 8 + e + 3] = f2bf(v.w);
      }
    }
#pragma unroll
    for (int q = 0; q < 4; ++q) *(uint4*)(dst + q * 8) = *(uint4*)(out + q * 8);
    return;
  }

  const float* W;
  short* Wt;
  int N, n0, k0;
  if (blk < 1280) {
    int i = blk - 512;
    W = Wq; Wt = Wqt; N = 3 * C_;
    n0 = (i % 48) * 64; k0 = (i / 48) * 64;
  } else {
    int i = blk - 1280;
    W = Wp; Wt = Wpt; N = C_;
    n0 = (i & 15) * 64; k0 = (i >> 4) * 64;
  }
  {
    int r = tid >> 2, c0 = (tid & 3) * 16;
    const float* src = W + (size_t)(k0 + r) * N + n0 + c0;
#pragma unroll
    for (int u = 0; u < 16; u += 4) {
      float4 v = *(const float4*)(src + u);
      Ts[r][c0 + u + 0] = f2bf(v.x);
      Ts[r][c0 + u + 1] = f2bf(v.y);
      Ts[r][c0 + u + 2] = f2bf(v.z);
      Ts[r][c0 + u + 3] = f2bf(v.w);
    }
  }
  __syncthreads();
  // write: 8 lanes cover one output row's 64 k (128 B contiguous, coalesced)
#pragma unroll
  for (int p = 0; p < 2; ++p) {
    int n = (tid >> 3) + p * 32;
    int kc = tid & 7;
    int xv = ((n0 + n) >> 1) & 3;
    int ka = kc * 8;
    int dk = (ka & ~31) | ((((ka >> 3) & 3) ^ xv) << 3);
    short tmp[8];
#pragma unroll
    for (int u = 0; u < 8; ++u) tmp[u] = Ts[ka + u][n];
    *(uint4*)(Wt + (size_t)(n0 + n) * 1024 + k0 + dk) = *(uint4*)tmp;
  }
}

// ---------------------------------------------------------------------------
// bf16 MFMA GEMM, 128xBN tile, BK=32, single-buffered LDS, 2-barrier K-loop
// (round-5 structure — measured best: qkv 43.6us, 0 conflicts, VGPR 80).
// KSPLIT: blockIdx.z splits the K range; KSPLIT>1 epilogue uses fp32
// atomicAdd into pre-zeroed Cout (bias added by the z==0 half only).
// QKV=true (BN=128): scatter epilogue -> attention-tiled Q/K/V:
//   Q,K: [bh][t>>6][d>>3][t&63][d&7]   (per-bh stride 131072 shorts)
//   V:   [bh][t>>6][(t&63)>>3][d][t&7],  Q pre-scaled by 1/sqrt(D).
// ---------------------------------------------------------------------------
template <int N, int BN, bool QKV, int KSPLIT>
__global__ __launch_bounds__(256) void gemm_mfma(
    const short* __restrict__ A, const short* __restrict__ Bt,
    const float* __restrict__ bias, short* __restrict__ Qp,
    short* __restrict__ Kp, short* __restrict__ Vp, float* __restrict__ Cout) {
  constexpr int NJ = BN / 32;  // n-tiles per wave
  constexpr int KL = 1024 / KSPLIT;
  const int tid = threadIdx.x;
  const int wave = tid >> 6, lane = tid & 63;
  const int quad = lane >> 4, l16 = lane & 15;
  const int wm = wave >> 1, wn = wave & 1;
  const int m0 = blockIdx.y * 128, n0 = blockIdx.x * BN;
  const int kbase = blockIdx.z * KL;

  __shared__ short As[128 * 32];
  __shared__ short Bs[BN * 32];

  const int srow = tid >> 2, skc = tid & 3;
  const size_t arow0 = (size_t)(m0 + srow) * 1024 + skc * 8;
  const size_t brow0 = (size_t)(n0 + srow) * 1024 + skc * 8;

  f32x4 acc[4][NJ] = {};

  const int xi = quad ^ ((l16 >> 1) & 3);  // de-swizzle chunk select
  int aoff[4], boff[NJ];
#pragma unroll
  for (int i = 0; i < 4; ++i) aoff[i] = (wm * 64 + i * 16 + l16) * 32 + xi * 8;
#pragma unroll
  for (int j = 0; j < NJ; ++j)
    boff[j] = (wn * (BN / 2) + j * 16 + l16) * 32 + xi * 8;

  for (int k0 = kbase; k0 < kbase + KL; k0 += 32) {
    __syncthreads();  // prior reads done before overwrite
    async16(A + arow0 + k0, As + tid * 8);
    async16(A + arow0 + (size_t)64 * 1024 + k0, As + 2048 + tid * 8);
    async16(Bt + brow0 + k0, Bs + tid * 8);
    if (BN == 128)
      async16(Bt + brow0 + (size_t)64 * 1024 + k0, Bs + 2048 + tid * 8);
    __syncthreads();  // staging visible (vmcnt drained by barrier)

    bf16x8 af[4], bfr[NJ];
#pragma unroll
    for (int i = 0; i < 4; ++i) af[i] = *(const bf16x8*)(As + aoff[i]);
#pragma unroll
    for (int j = 0; j < NJ; ++j) bfr[j] = *(const bf16x8*)(Bs + boff[j]);
#pragma unroll
    for (int i = 0; i < 4; ++i)
#pragma unroll
      for (int j = 0; j < NJ; ++j)
        acc[i][j] = __builtin_amdgcn_mfma_f32_16x16x32_bf16(af[i], bfr[j],
                                                            acc[i][j], 0, 0, 0);
  }

  float bj[NJ];
#pragma unroll
  for (int j = 0; j < NJ; ++j) {
    float bv = bias[n0 + wn * (BN / 2) + j * 16 + l16];
    bj[j] = (KSPLIT > 1 && blockIdx.z != 0) ? 0.f : bv;
  }

  if (QKV) {
#pragma unroll
    for (int i = 0; i < 4; ++i) {
#pragma unroll
      for (int reg = 0; reg < 4; ++reg) {
        int m = m0 + wm * 64 + i * 16 + quad * 4 + reg;
        int b = m >> 11, t = m & (T_ - 1);
#pragma unroll
        for (int j = 0; j < NJ; ++j) {
          int n = n0 + wn * (BN / 2) + j * 16 + l16;
          float v = acc[i][j][reg] + bj[j];
          int sel = n >> 10, cc = n & (C_ - 1);
          int hh = cc >> 6, d = cc & 63;
          size_t base = (size_t)(b * H_ + hh) * 131072 + (size_t)(t >> 6) * 4096;
          if (sel == 0) {
            Qp[base + (d >> 3) * 512 + (t & 63) * 8 + (d & 7)] = f2bf(v * 0.125f);
          } else if (sel == 1) {
            Kp[base + (d >> 3) * 512 + (t & 63) * 8 + (d & 7)] = f2bf(v);
          } else {
            Vp[base + ((t & 63) >> 3) * 512 + d * 8 + (t & 7)] = f2bf(v);
          }
        }
      }
    }
  } else {
#pragma unroll
    for (int i = 0; i < 4; ++i) {
#pragma unroll
      for (int reg = 0; reg < 4; ++reg) {
        int m = m0 + wm * 64 + i * 16 + quad * 4 + reg;
#pragma unroll
        for (int j = 0; j < NJ; ++j) {
          int n = n0 + wn * (BN / 2) + j * 16 + l16;
          float v = acc[i][j][reg] + bj[j];
          if (KSPLIT > 1) {
            unsafeAtomicAdd(&Cout[(size_t)m * N + n], v);
          } else {
            Cout[(size_t)m * N + n] = v;
          }
        }
      }
    }
  }
}

// ---------------------------------------------------------------------------
// bf16 MFMA flash attention, S^T formulation, static softmax, one barrier per
// tile, double-buffered K/V prefetch (verified round 5).
// ---------------------------------------------------------------------------
__global__ __launch_bounds__(256, 4) void attn_kernel(
    const short* __restrict__ Qt, const short* __restrict__ Kt,
    const short* __restrict__ Vt, short* __restrict__ attb) {
  const int tid = threadIdx.x;
  const int wave = tid >> 6, lane = tid & 63;
  const int quad = lane >> 4, l16 = lane & 15;

  const int blk = blockIdx.x;
  const int bh = (blk >> 5) & 31;
  const int k2 = blk >> 8;
  int qtt = ((blk & 31) + 8 * (k2 >> 1)) & 31;
  const int qt = (k2 & 1) ? (31 - qtt) : qtt;
  const int h = bh & 15, b = bh >> 4;
  const int q0 = qt * 64;

  const short* Qg = Qt + (size_t)bh * 131072;
  const short* Kg = Kt + (size_t)bh * 131072;
  const short* Vg = Vt + (size_t)bh * 131072;

  __shared__ short Ks[2][4096];
  __shared__ short Vs[2][4096];
  __shared__ short Ps[4096];

  const int rowl = 16 * wave + l16;

  bf16x8 bq[2];
#pragma unroll
  for (int f = 0; f < 2; ++f)
    bq[f] = *(const bf16x8*)(Qg + (size_t)(qt * 8 + 4 * f + quad) * 512 +
                             rowl * 8);

  async16(Kg + tid * 8, &Ks[0][tid * 8]);
  async16(Kg + 2048 + tid * 8, &Ks[0][2048 + tid * 8]);
  async16(Vg + tid * 8, &Vs[0][tid * 8]);
  async16(Vg + 2048 + tid * 8, &Vs[0][2048 + tid * 8]);

  f32x4 oacc[4] = {};
  float lsum = 0.f;

  for (int kt = 0; kt <= qt; ++kt) {
    const int buf = kt & 1;
    __syncthreads();
    if (kt < qt) {
      const short* kp = Kg + (size_t)(kt + 1) * 4096;
      const short* vp = Vg + (size_t)(kt + 1) * 4096;
      async16(kp + tid * 8, &Ks[buf ^ 1][tid * 8]);
      async16(kp + 2048 + tid * 8, &Ks[buf ^ 1][2048 + tid * 8]);
      async16(vp + tid * 8, &Vs[buf ^ 1][tid * 8]);
      async16(vp + 2048 + tid * 8, &Vs[buf ^ 1][2048 + tid * 8]);
    }

    f32x4 sacc[4] = {};
#pragma unroll
    for (int c = 0; c < 4; ++c) {
#pragma unroll
      for (int f = 0; f < 2; ++f) {
        bf16x8 ak = *(const bf16x8*)&Ks[buf][((4 * f + quad) * 64 + 16 * c + l16) * 8];
        sacc[c] = __builtin_amdgcn_mfma_f32_16x16x32_bf16(ak, bq[f], sacc[c], 0, 0, 0);
      }
    }

    const bool diag = (kt == qt);
#pragma unroll
    for (int c = 0; c < 4; ++c) {
      short4 pk;
#pragma unroll
      for (int reg = 0; reg < 4; ++reg) {
        int keyl = 16 * c + 4 * quad + reg;
        float p = (diag && keyl > rowl) ? 0.f : __expf(sacc[c][reg]);
        lsum += p;
        ((short*)&pk)[reg] = f2bf(p);
      }
      *(short4*)&Ps[(2 * c + (quad >> 1)) * 512 + rowl * 8 + (quad & 1) * 4] = pk;
    }

    __asm__ volatile("s_waitcnt lgkmcnt(0)" ::: "memory");

    bf16x8 ap[2];
#pragma unroll
    for (int f = 0; f < 2; ++f)
      ap[f] = *(const bf16x8*)&Ps[(4 * f + quad) * 512 + rowl * 8];
#pragma unroll
    for (int n = 0; n < 4; ++n) {
#pragma unroll
      for (int f = 0; f < 2; ++f) {
        bf16x8 bv = *(const bf16x8*)&Vs[buf][((4 * f + quad) * 64 + 16 * n + l16) * 8];
        oacc[n] = __builtin_amdgcn_mfma_f32_16x16x32_bf16(ap[f], bv, oacc[n], 0, 0, 0);
      }
    }
  }

  lsum += __shfl_xor(lsum, 16);
  lsum += __shfl_xor(lsum, 32);
  float linv[4];
#pragma unroll
  for (int reg = 0; reg < 4; ++reg)
    linv[reg] = 1.0f / __shfl(lsum, 4 * quad + reg, 64);

#pragma unroll
  for (int reg = 0; reg < 4; ++reg) {
    const int row = q0 + 16 * wave + 4 * quad + reg;
    const int m = b * T_ + row;
    const int xv = (m >> 1) & 3;
#pragma unroll
    for (int n = 0; n < 4; ++n) {
      int c = h * 64 + 16 * n + l16;
      int cs = (c & ~31) | ((((c >> 3) & 3) ^ xv) << 3) | (c & 7);
      attb[(size_t)m * C_ + cs] = f2bf(oacc[n][reg] * linv[reg]);
    }
  }
}

extern "C" void kernel_launch(void* const* d_in, const int* in_sizes, int n_in,
                              void* d_out, int out_size, void* d_ws, size_t ws_size,
                              hipStream_t stream) {
  const float* x      = (const float*)d_in[0];
  const float* w_qkv  = (const float*)d_in[1];
  const float* b_qkv  = (const float*)d_in[2];
  const float* w_proj = (const float*)d_in[3];
  const float* b_proj = (const float*)d_in[4];
  float* out = (float*)d_out;

  const size_t per = (size_t)B_ * H_ * T_ * D_;  // 4.19M
  short* Qp   = (short*)d_ws;
  short* Kp   = Qp + per;
  short* Vp   = Kp + per;
  short* attb = Vp + per;                   // [4096,1024] bf16 swizzled
  short* xb   = attb + per;                 // [4096,1024] bf16 swizzled
  short* wqt  = xb + per;                   // [3072,1024] bf16 swizzled
  short* wpt  = wqt + (size_t)3 * C_ * C_;  // [1024,1024] bf16 swizzled

  // zero d_out for split-K atomic accumulation (graph-capturable)
  hipMemsetAsync(out, 0, (size_t)out_size * sizeof(float), stream);

  prep<<<1536, 256, 0, stream>>>(x, w_qkv, w_proj, xb, wqt, wpt);

  gemm_mfma<3 * C_, 128, true, 1><<<dim3(24, 32, 1), 256, 0, stream>>>(
      xb, wqt, b_qkv, Qp, Kp, Vp, nullptr);

  attn_kernel<<<dim3(1024), 256, 0, stream>>>(Qp, Kp, Vp, attb);

  gemm_mfma<C_, 128, false, 2><<<dim3(8, 32, 2), 256, 0, stream>>>(
      attb, wpt, b_proj, nullptr, nullptr, nullptr, out);
}

// Round 9
// 175.814 us; speedup vs baseline: 1.1497x; 1.1497x over previous
//
#include <hip/hip_runtime.h>
#include <hip/hip_bf16.h>
#include <math.h>
#include <stdint.h>

#define B_ 2
#define T_ 2048
#define C_ 1024
#define H_ 16
#define D_ 64

typedef __attribute__((ext_vector_type(8))) short bf16x8;
typedef __attribute__((ext_vector_type(4))) float f32x4;

__device__ inline short f2bf(float f) {
  __hip_bfloat16 h = __float2bfloat16(f);
  return *(short*)&h;
}

// async global->LDS, 16B/lane. LDS image = wave-uniform base + lane*16.
__device__ inline void async16(const void* g, void* l) {
  __builtin_amdgcn_global_load_lds(
      (const __attribute__((address_space(1))) uint32_t*)g,
      (__attribute__((address_space(3))) uint32_t*)l, 16, 0, 0);
}

// ---------------------------------------------------------------------------
// Swizzle convention for GEMM operand images (A [M,1024] and B^T [N,1024]):
// chunk p of each 32-k group holds source chunk (p ^ ((row>>1)&3)).
// Fragment reads use chunk (quad ^ ((l16>>1)&3)) -> 2-way banks (free).
// ---------------------------------------------------------------------------

// One prep kernel: blocks [0,512) convert x -> bf16 swizzled;
// [512,1280) transpose w_qkv; [1280,1536) transpose w_proj.
__global__ __launch_bounds__(256) void prep(
    const float* __restrict__ X, const float* __restrict__ Wq,
    const float* __restrict__ Wp, short* __restrict__ Xb,
    short* __restrict__ Wqt, short* __restrict__ Wpt) {
  const int tid = threadIdx.x;
  const int blk = blockIdx.x;
  __shared__ short Ts[64][68];

  if (blk < 512) {  // convert_x: one 32-k group per thread
    int t = blk * 256 + tid;
    int m = t >> 5, g = t & 31;
    const float* src = X + (size_t)m * C_ + g * 32;
    short* dst = Xb + (size_t)m * C_ + g * 32;
    int xv = (m >> 1) & 3;
    short out[32];
#pragma unroll
    for (int ch = 0; ch < 4; ++ch) {
      int sc = ch ^ xv;
#pragma unroll
      for (int e = 0; e < 8; e += 4) {
        float4 v = *(const float4*)(src + sc * 8 + e);
        out[ch * 8 + e + 0] = f2bf(v.x);
        out[ch * 8 + e + 1] = f2bf(v.y);
        out[ch * 8 + e + 2] = f2bf(v.z);
        out[ch * 8 + e + 3] = f2bf(v.w);
      }
    }
#pragma unroll
    for (int q = 0; q < 4; ++q) *(uint4*)(dst + q * 8) = *(uint4*)(out + q * 8);
    return;
  }

  const float* W;
  short* Wt;
  int N, n0, k0;
  if (blk < 1280) {
    int i = blk - 512;
    W = Wq; Wt = Wqt; N = 3 * C_;
    n0 = (i % 48) * 64; k0 = (i / 48) * 64;
  } else {
    int i = blk - 1280;
    W = Wp; Wt = Wpt; N = C_;
    n0 = (i & 15) * 64; k0 = (i >> 4) * 64;
  }
  {
    int r = tid >> 2, c0 = (tid & 3) * 16;
    const float* src = W + (size_t)(k0 + r) * N + n0 + c0;
#pragma unroll
    for (int u = 0; u < 16; u += 4) {
      float4 v = *(const float4*)(src + u);
      Ts[r][c0 + u + 0] = f2bf(v.x);
      Ts[r][c0 + u + 1] = f2bf(v.y);
      Ts[r][c0 + u + 2] = f2bf(v.z);
      Ts[r][c0 + u + 3] = f2bf(v.w);
    }
  }
  __syncthreads();
  // write: 8 lanes cover one output row's 64 k (128 B contiguous, coalesced)
#pragma unroll
  for (int p = 0; p < 2; ++p) {
    int n = (tid >> 3) + p * 32;
    int kc = tid & 7;
    int xv = ((n0 + n) >> 1) & 3;
    int ka = kc * 8;
    int dk = (ka & ~31) | ((((ka >> 3) & 3) ^ xv) << 3);
    short tmp[8];
#pragma unroll
    for (int u = 0; u < 8; ++u) tmp[u] = Ts[ka + u][n];
    *(uint4*)(Wt + (size_t)(n0 + n) * 1024 + k0 + dk) = *(uint4*)tmp;
  }
}

// ---------------------------------------------------------------------------
// bf16 MFMA GEMM, 128xBN tile, BK=64 staged as TWO consecutive BK=32 images
// in the round-5 conflict-free swizzled [row][32k] layout (identical bytes,
// just two of them): half the barrier drains, 2x MFMA per drain, 0 conflicts.
// QKV=true (BN=128): scatter epilogue -> attention-tiled Q/K/V:
//   Q,K: [bh][t>>6][d>>3][t&63][d&7]   (per-bh stride 131072 shorts)
//   V:   [bh][t>>6][(t&63)>>3][d][t&7],  Q pre-scaled by 1/sqrt(D).
// ---------------------------------------------------------------------------
template <int N, int BN, bool QKV>
__global__ __launch_bounds__(256) void gemm_mfma(
    const short* __restrict__ A, const short* __restrict__ Bt,
    const float* __restrict__ bias, short* __restrict__ Qp,
    short* __restrict__ Kp, short* __restrict__ Vp, float* __restrict__ Cout) {
  constexpr int NJ = BN / 32;      // n-tiles per wave
  constexpr int BI = BN * 32;      // B image size (shorts)
  const int tid = threadIdx.x;
  const int wave = tid >> 6, lane = tid & 63;
  const int quad = lane >> 4, l16 = lane & 15;
  const int wm = wave >> 1, wn = wave & 1;
  const int m0 = blockIdx.y * 128, n0 = blockIdx.x * BN;

  __shared__ short As[2][4096];    // two 32-k images, [row][32k] swizzled
  __shared__ short Bs[2][BI];

  const int srow = tid >> 2, skc = tid & 3;
  const size_t arow0 = (size_t)(m0 + srow) * 1024 + skc * 8;
  const size_t brow0 = (size_t)(n0 + srow) * 1024 + skc * 8;

  f32x4 acc[4][NJ] = {};

  const int xi = quad ^ ((l16 >> 1) & 3);  // de-swizzle chunk select
  int aoff[4], boff[NJ];
#pragma unroll
  for (int i = 0; i < 4; ++i) aoff[i] = (wm * 64 + i * 16 + l16) * 32 + xi * 8;
#pragma unroll
  for (int j = 0; j < NJ; ++j)
    boff[j] = (wn * (BN / 2) + j * 16 + l16) * 32 + xi * 8;

  for (int k0 = 0; k0 < 1024; k0 += 64) {
    __syncthreads();  // prior reads done before overwrite
#pragma unroll
    for (int f = 0; f < 2; ++f) {
      const int kf = k0 + f * 32;
      async16(A + arow0 + kf, &As[f][tid * 8]);
      async16(A + arow0 + (size_t)64 * 1024 + kf, &As[f][2048 + tid * 8]);
      async16(Bt + brow0 + kf, &Bs[f][tid * 8]);
      if (BN == 128)
        async16(Bt + brow0 + (size_t)64 * 1024 + kf, &Bs[f][2048 + tid * 8]);
    }
    __syncthreads();  // staging visible (vmcnt drained by barrier)

#pragma unroll
    for (int f = 0; f < 2; ++f) {
      bf16x8 af[4], bfr[NJ];
#pragma unroll
      for (int i = 0; i < 4; ++i) af[i] = *(const bf16x8*)&As[f][aoff[i]];
#pragma unroll
      for (int j = 0; j < NJ; ++j) bfr[j] = *(const bf16x8*)&Bs[f][boff[j]];
#pragma unroll
      for (int i = 0; i < 4; ++i)
#pragma unroll
        for (int j = 0; j < NJ; ++j)
          acc[i][j] = __builtin_amdgcn_mfma_f32_16x16x32_bf16(
              af[i], bfr[j], acc[i][j], 0, 0, 0);
    }
  }

  float bj[NJ];
#pragma unroll
  for (int j = 0; j < NJ; ++j) bj[j] = bias[n0 + wn * (BN / 2) + j * 16 + l16];

  if (QKV) {
#pragma unroll
    for (int i = 0; i < 4; ++i) {
#pragma unroll
      for (int reg = 0; reg < 4; ++reg) {
        int m = m0 + wm * 64 + i * 16 + quad * 4 + reg;
        int b = m >> 11, t = m & (T_ - 1);
#pragma unroll
        for (int j = 0; j < NJ; ++j) {
          int n = n0 + wn * (BN / 2) + j * 16 + l16;
          float v = acc[i][j][reg] + bj[j];
          int sel = n >> 10, cc = n & (C_ - 1);
          int hh = cc >> 6, d = cc & 63;
          size_t base = (size_t)(b * H_ + hh) * 131072 + (size_t)(t >> 6) * 4096;
          if (sel == 0) {
            Qp[base + (d >> 3) * 512 + (t & 63) * 8 + (d & 7)] = f2bf(v * 0.125f);
          } else if (sel == 1) {
            Kp[base + (d >> 3) * 512 + (t & 63) * 8 + (d & 7)] = f2bf(v);
          } else {
            Vp[base + ((t & 63) >> 3) * 512 + d * 8 + (t & 7)] = f2bf(v);
          }
        }
      }
    }
  } else {
#pragma unroll
    for (int i = 0; i < 4; ++i) {
#pragma unroll
      for (int reg = 0; reg < 4; ++reg) {
        int m = m0 + wm * 64 + i * 16 + quad * 4 + reg;
#pragma unroll
        for (int j = 0; j < NJ; ++j) {
          int n = n0 + wn * (BN / 2) + j * 16 + l16;
          Cout[(size_t)m * N + n] = acc[i][j][reg] + bj[j];
        }
      }
    }
  }
}

// ---------------------------------------------------------------------------
// bf16 MFMA flash attention, S^T formulation, static softmax, one barrier per
// tile, double-buffered K/V prefetch (verified round 5).
// ---------------------------------------------------------------------------
__global__ __launch_bounds__(256, 4) void attn_kernel(
    const short* __restrict__ Qt, const short* __restrict__ Kt,
    const short* __restrict__ Vt, short* __restrict__ attb) {
  const int tid = threadIdx.x;
  const int wave = tid >> 6, lane = tid & 63;
  const int quad = lane >> 4, l16 = lane & 15;

  const int blk = blockIdx.x;
  const int bh = (blk >> 5) & 31;
  const int k2 = blk >> 8;
  int qtt = ((blk & 31) + 8 * (k2 >> 1)) & 31;
  const int qt = (k2 & 1) ? (31 - qtt) : qtt;
  const int h = bh & 15, b = bh >> 4;
  const int q0 = qt * 64;

  const short* Qg = Qt + (size_t)bh * 131072;
  const short* Kg = Kt + (size_t)bh * 131072;
  const short* Vg = Vt + (size_t)bh * 131072;

  __shared__ short Ks[2][4096];
  __shared__ short Vs[2][4096];
  __shared__ short Ps[4096];

  const int rowl = 16 * wave + l16;

  bf16x8 bq[2];
#pragma unroll
  for (int f = 0; f < 2; ++f)
    bq[f] = *(const bf16x8*)(Qg + (size_t)(qt * 8 + 4 * f + quad) * 512 +
                             rowl * 8);

  async16(Kg + tid * 8, &Ks[0][tid * 8]);
  async16(Kg + 2048 + tid * 8, &Ks[0][2048 + tid * 8]);
  async16(Vg + tid * 8, &Vs[0][tid * 8]);
  async16(Vg + 2048 + tid * 8, &Vs[0][2048 + tid * 8]);

  f32x4 oacc[4] = {};
  float lsum = 0.f;

  for (int kt = 0; kt <= qt; ++kt) {
    const int buf = kt & 1;
    __syncthreads();
    if (kt < qt) {
      const short* kp = Kg + (size_t)(kt + 1) * 4096;
      const short* vp = Vg + (size_t)(kt + 1) * 4096;
      async16(kp + tid * 8, &Ks[buf ^ 1][tid * 8]);
      async16(kp + 2048 + tid * 8, &Ks[buf ^ 1][2048 + tid * 8]);
      async16(vp + tid * 8, &Vs[buf ^ 1][tid * 8]);
      async16(vp + 2048 + tid * 8, &Vs[buf ^ 1][2048 + tid * 8]);
    }

    f32x4 sacc[4] = {};
#pragma unroll
    for (int c = 0; c < 4; ++c) {
#pragma unroll
      for (int f = 0; f < 2; ++f) {
        bf16x8 ak = *(const bf16x8*)&Ks[buf][((4 * f + quad) * 64 + 16 * c + l16) * 8];
        sacc[c] = __builtin_amdgcn_mfma_f32_16x16x32_bf16(ak, bq[f], sacc[c], 0, 0, 0);
      }
    }

    const bool diag = (kt == qt);
#pragma unroll
    for (int c = 0; c < 4; ++c) {
      short4 pk;
#pragma unroll
      for (int reg = 0; reg < 4; ++reg) {
        int keyl = 16 * c + 4 * quad + reg;
        float p = (diag && keyl > rowl) ? 0.f : __expf(sacc[c][reg]);
        lsum += p;
        ((short*)&pk)[reg] = f2bf(p);
      }
      *(short4*)&Ps[(2 * c + (quad >> 1)) * 512 + rowl * 8 + (quad & 1) * 4] = pk;
    }

    __asm__ volatile("s_waitcnt lgkmcnt(0)" ::: "memory");

    bf16x8 ap[2];
#pragma unroll
    for (int f = 0; f < 2; ++f)
      ap[f] = *(const bf16x8*)&Ps[(4 * f + quad) * 512 + rowl * 8];
#pragma unroll
    for (int n = 0; n < 4; ++n) {
#pragma unroll
      for (int f = 0; f < 2; ++f) {
        bf16x8 bv = *(const bf16x8*)&Vs[buf][((4 * f + quad) * 64 + 16 * n + l16) * 8];
        oacc[n] = __builtin_amdgcn_mfma_f32_16x16x32_bf16(ap[f], bv, oacc[n], 0, 0, 0);
      }
    }
  }

  lsum += __shfl_xor(lsum, 16);
  lsum += __shfl_xor(lsum, 32);
  float linv[4];
#pragma unroll
  for (int reg = 0; reg < 4; ++reg)
    linv[reg] = 1.0f / __shfl(lsum, 4 * quad + reg, 64);

#pragma unroll
  for (int reg = 0; reg < 4; ++reg) {
    const int row = q0 + 16 * wave + 4 * quad + reg;
    const int m = b * T_ + row;
    const int xv = (m >> 1) & 3;
#pragma unroll
    for (int n = 0; n < 4; ++n) {
      int c = h * 64 + 16 * n + l16;
      int cs = (c & ~31) | ((((c >> 3) & 3) ^ xv) << 3) | (c & 7);
      attb[(size_t)m * C_ + cs] = f2bf(oacc[n][reg] * linv[reg]);
    }
  }
}

extern "C" void kernel_launch(void* const* d_in, const int* in_sizes, int n_in,
                              void* d_out, int out_size, void* d_ws, size_t ws_size,
                              hipStream_t stream) {
  const float* x      = (const float*)d_in[0];
  const float* w_qkv  = (const float*)d_in[1];
  const float* b_qkv  = (const float*)d_in[2];
  const float* w_proj = (const float*)d_in[3];
  const float* b_proj = (const float*)d_in[4];
  float* out = (float*)d_out;

  const size_t per = (size_t)B_ * H_ * T_ * D_;  // 4.19M
  short* Qp   = (short*)d_ws;
  short* Kp   = Qp + per;
  short* Vp   = Kp + per;
  short* attb = Vp + per;                   // [4096,1024] bf16 swizzled
  short* xb   = attb + per;                 // [4096,1024] bf16 swizzled
  short* wqt  = xb + per;                   // [3072,1024] bf16 swizzled
  short* wpt  = wqt + (size_t)3 * C_ * C_;  // [1024,1024] bf16 swizzled

  prep<<<1536, 256, 0, stream>>>(x, w_qkv, w_proj, xb, wqt, wpt);

  gemm_mfma<3 * C_, 128, true><<<dim3(24, 32), 256, 0, stream>>>(
      xb, wqt, b_qkv, Qp, Kp, Vp, nullptr);

  attn_kernel<<<dim3(1024), 256, 0, stream>>>(Qp, Kp, Vp, attb);

  gemm_mfma<C_, 64, false><<<dim3(16, 32), 256, 0, stream>>>(
      attb, wpt, b_proj, nullptr, nullptr, nullptr, out);
}